// Round 1
// baseline (600.574 us; speedup 1.0000x reference)
//
#include <hip/hip_runtime.h>
#include <hip/hip_bf16.h>
#include <math.h>

// ---- problem constants (structural, from the reference) ----
#define NB      2
#define QN      12240            // Q == HW
#define HW_TOT  12240
#define DIMS    256
#define HEADS   8
#define CH      32
#define LEVELS  4
#define POINTS  4

// level shapes & starts: (96,96),(48,48),(24,24),(12,12)
__device__ __constant__ int c_Hl[4]    = {96, 48, 24, 12};
__device__ __constant__ int c_Wl[4]    = {96, 48, 24, 12};
__device__ __constant__ int c_start[4] = {0, 9216, 11520, 12096};

// =====================================================================
// Tiled fp32 SGEMM with bias: C[M,Nc] = A[M,K] @ B[K,Nc] + bias[Nc]
// 64x64 tile, K-chunk 16, 256 threads, 4x4 micro-tile per thread.
// Nc and K must be multiples of 64 / 16 (true here: Nc in {128,256}, K=256).
// =====================================================================
#define TM 64
#define TN 64
#define TK 16

__global__ __launch_bounds__(256) void sgemm_bias_kernel(
    const float* __restrict__ A, const float* __restrict__ B,
    const float* __restrict__ bias, float* __restrict__ C,
    int M, int Nc, int K)
{
    __shared__ float As[TK][TM];   // As[k][m]
    __shared__ float Bs[TK][TN];   // Bs[k][n]

    const int tid = threadIdx.x;
    const int bm0 = blockIdx.x * TM;
    const int bn0 = blockIdx.y * TN;
    const int tx = tid & 15;       // 0..15 -> 4 cols each
    const int ty = tid >> 4;       // 0..15 -> 4 rows each

    float acc[4][4] = {};

    for (int kk = 0; kk < K; kk += TK) {
        // load A tile (64 rows x 16 cols), transposed into As[k][m]
        #pragma unroll
        for (int u = 0; u < 4; ++u) {
            int f = tid + 256 * u;          // 0..1023
            int r = f >> 4, cc = f & 15;
            float val = 0.0f;
            int gr = bm0 + r;
            if (gr < M) val = A[(size_t)gr * K + kk + cc];
            As[cc][r] = val;
        }
        // load B tile (16 rows x 64 cols)
        #pragma unroll
        for (int u = 0; u < 4; ++u) {
            int f = tid + 256 * u;
            int r = f >> 6, cc = f & 63;
            Bs[r][cc] = B[(size_t)(kk + r) * Nc + bn0 + cc];
        }
        __syncthreads();

        #pragma unroll
        for (int k = 0; k < TK; ++k) {
            float a[4], b[4];
            #pragma unroll
            for (int i = 0; i < 4; ++i) a[i] = As[k][ty * 4 + i];
            #pragma unroll
            for (int j = 0; j < 4; ++j) b[j] = Bs[k][tx * 4 + j];
            #pragma unroll
            for (int i = 0; i < 4; ++i)
                #pragma unroll
                for (int j = 0; j < 4; ++j)
                    acc[i][j] += a[i] * b[j];
        }
        __syncthreads();
    }

    #pragma unroll
    for (int i = 0; i < 4; ++i) {
        int gr = bm0 + ty * 4 + i;
        if (gr >= M) continue;
        #pragma unroll
        for (int j = 0; j < 4; ++j) {
            int gc = bn0 + tx * 4 + j;
            C[(size_t)gr * Nc + gc] = acc[i][j] + bias[gc];
        }
    }
}

// =====================================================================
// Sampling kernel: one block per (n,q); 256 threads = 8 heads x 32 ch.
// Reads:
//   vproj  [N, HW, HEADS, CH]   (flat (n*HW+pos)*256 + h*32 + c)
//   offs   [N, Q, HEADS, L, P, 2]
//   logits [N, Q, HEADS, L*P]
//   p      [N, Q, L, 2]
// Writes:
//   mid    [N, Q, 256]
// =====================================================================
__global__ __launch_bounds__(256) void msda_sample_kernel(
    const float* __restrict__ vproj, const float* __restrict__ offs,
    const float* __restrict__ logits, const float* __restrict__ p,
    float* __restrict__ mid)
{
    const int nq = blockIdx.x;            // 0 .. N*Q-1
    const int n  = nq / QN;
    const int tid = threadIdx.x;
    const int h = tid >> 5;               // 0..7
    const int c = tid & 31;               // 0..31

    __shared__ float s_logit[HEADS * LEVELS * POINTS];   // 128
    __shared__ float s_off[DIMS];                        // 256
    __shared__ float s_p[LEVELS * 2];                    // 8

    if (tid < 128) s_logit[tid] = logits[(size_t)nq * 128 + tid];
    s_off[tid] = offs[(size_t)nq * 256 + tid];
    if (tid < 8)  s_p[tid] = p[(size_t)nq * 8 + tid];
    __syncthreads();

    // softmax (over the 16 logits of head h) -- each lane redundantly
    float mx = -1e30f;
    #pragma unroll
    for (int i = 0; i < 16; ++i) mx = fmaxf(mx, s_logit[h * 16 + i]);
    float ssum = 0.0f;
    #pragma unroll
    for (int i = 0; i < 16; ++i) ssum += __expf(s_logit[h * 16 + i] - mx);
    const float inv = 1.0f / ssum;

    const float* vbase = vproj + (size_t)n * HW_TOT * DIMS + h * CH + c;

    float acc = 0.0f;
    #pragma unroll
    for (int l = 0; l < LEVELS; ++l) {
        const int Hl = c_Hl[l], Wl = c_Wl[l], st = c_start[l];
        const float fW = (float)Wl, fH = (float)Hl;
        const float px = s_p[l * 2 + 0];
        const float py = s_p[l * 2 + 1];
        #pragma unroll
        for (int pt = 0; pt < POINTS; ++pt) {
            const int oi = (((h * LEVELS + l) * POINTS) + pt) * 2;
            const float ox = s_off[oi];
            const float oy = s_off[oi + 1];
            const float w = __expf(s_logit[h * 16 + l * 4 + pt] - mx) * inv;

            // mirror reference arithmetic: loc = p + off/(W,H); x = loc*W - 0.5
            const float lx = px + ox / fW;
            const float ly = py + oy / fH;
            const float x = lx * fW - 0.5f;
            const float y = ly * fH - 0.5f;

            const float x0f = floorf(x), y0f = floorf(y);
            const int x0 = (int)x0f, y0 = (int)y0f;
            const float dx = x - x0f, dy = y - y0f;

            const float w00 = (1.0f - dx) * (1.0f - dy);
            const float w10 = dx * (1.0f - dy);
            const float w01 = (1.0f - dx) * dy;
            const float w11 = dx * dy;

            // corner (x0, y0)
            if (x0 >= 0 && x0 < Wl && y0 >= 0 && y0 < Hl)
                acc += w * w00 * vbase[(size_t)(st + y0 * Wl + x0) * DIMS];
            // corner (x0+1, y0)
            if (x0 + 1 >= 0 && x0 + 1 < Wl && y0 >= 0 && y0 < Hl)
                acc += w * w10 * vbase[(size_t)(st + y0 * Wl + x0 + 1) * DIMS];
            // corner (x0, y0+1)
            if (x0 >= 0 && x0 < Wl && y0 + 1 >= 0 && y0 + 1 < Hl)
                acc += w * w01 * vbase[(size_t)(st + (y0 + 1) * Wl + x0) * DIMS];
            // corner (x0+1, y0+1)
            if (x0 + 1 >= 0 && x0 + 1 < Wl && y0 + 1 >= 0 && y0 + 1 < Hl)
                acc += w * w11 * vbase[(size_t)(st + (y0 + 1) * Wl + x0 + 1) * DIMS];
        }
    }

    mid[(size_t)nq * DIMS + tid] = acc;
}

// =====================================================================
extern "C" void kernel_launch(void* const* d_in, const int* in_sizes, int n_in,
                              void* d_out, int out_size, void* d_ws, size_t ws_size,
                              hipStream_t stream)
{
    const float* q      = (const float*)d_in[0];
    const float* p      = (const float*)d_in[1];
    const float* v      = (const float*)d_in[2];
    const float* W_off  = (const float*)d_in[3];
    const float* b_off  = (const float*)d_in[4];
    const float* W_attn = (const float*)d_in[5];
    const float* b_attn = (const float*)d_in[6];
    const float* W_in   = (const float*)d_in[7];
    const float* b_in   = (const float*)d_in[8];
    const float* W_out  = (const float*)d_in[9];
    const float* b_out  = (const float*)d_in[10];
    float* out = (float*)d_out;

    const int M = NB * QN;                         // 24480

    // workspace layout (floats)
    float* vproj  = (float*)d_ws;                  // N*HW*256 = 6,266,880
    float* offs   = vproj + (size_t)NB * HW_TOT * DIMS;
    float* logit  = offs  + (size_t)NB * QN * DIMS;      // N*Q*256
    float* mid    = logit + (size_t)NB * QN * 128;       // N*Q*128

    const int gx = (M + TM - 1) / TM;              // 383

    // 1) v_proj = v @ W_in + b_in
    sgemm_bias_kernel<<<dim3(gx, DIMS / TN), 256, 0, stream>>>(
        v, W_in, b_in, vproj, M, DIMS, DIMS);
    // 2) offsets = q @ W_off + b_off
    sgemm_bias_kernel<<<dim3(gx, DIMS / TN), 256, 0, stream>>>(
        q, W_off, b_off, offs, M, DIMS, DIMS);
    // 3) attn logits = q @ W_attn + b_attn
    sgemm_bias_kernel<<<dim3(gx, 128 / TN), 256, 0, stream>>>(
        q, W_attn, b_attn, logit, M, 128, DIMS);
    // 4) softmax + bilinear sampling + attention-weighted sum
    msda_sample_kernel<<<dim3(M), 256, 0, stream>>>(vproj, offs, logit, p, mid);
    // 5) out = mid @ W_out + b_out
    sgemm_bias_kernel<<<dim3(gx, DIMS / TN), 256, 0, stream>>>(
        mid, W_out, b_out, out, M, DIMS, DIMS);
}

// Round 2
// 420.354 us; speedup vs baseline: 1.4287x; 1.4287x over previous
//
#include <hip/hip_runtime.h>
#include <hip/hip_bf16.h>
#include <math.h>

// ---- problem constants (structural, from the reference) ----
#define NB      2
#define QN      12240            // Q == HW
#define HW_TOT  12240
#define DIMS    256
#define HEADS   8
#define CH      32
#define LEVELS  4
#define POINTS  4

// level shapes & starts: (96,96),(48,48),(24,24),(12,12)
__device__ __constant__ int c_Hl[4]    = {96, 48, 24, 12};
__device__ __constant__ int c_Wl[4]    = {96, 48, 24, 12};
__device__ __constant__ int c_start[4] = {0, 9216, 11520, 12096};

// =====================================================================
// Tiled fp32 SGEMM with bias: C[M,Nc] = A[M,K] @ B[K,Nc] + bias[Nc]
// 64x64 tile, K-chunk 16, 256 threads, 4x4 micro-tile per thread.
// (unchanged from round 1 -- bf16 MFMA is a future round)
// =====================================================================
#define TM 64
#define TN 64
#define TK 16

__global__ __launch_bounds__(256) void sgemm_bias_kernel(
    const float* __restrict__ A, const float* __restrict__ B,
    const float* __restrict__ bias, float* __restrict__ C,
    int M, int Nc, int K)
{
    __shared__ float As[TK][TM];   // As[k][m]
    __shared__ float Bs[TK][TN];   // Bs[k][n]

    const int tid = threadIdx.x;
    const int bm0 = blockIdx.x * TM;
    const int bn0 = blockIdx.y * TN;
    const int tx = tid & 15;       // 0..15 -> 4 cols each
    const int ty = tid >> 4;       // 0..15 -> 4 rows each

    float acc[4][4] = {};

    for (int kk = 0; kk < K; kk += TK) {
        #pragma unroll
        for (int u = 0; u < 4; ++u) {
            int f = tid + 256 * u;          // 0..1023
            int r = f >> 4, cc = f & 15;
            float val = 0.0f;
            int gr = bm0 + r;
            if (gr < M) val = A[(size_t)gr * K + kk + cc];
            As[cc][r] = val;
        }
        #pragma unroll
        for (int u = 0; u < 4; ++u) {
            int f = tid + 256 * u;
            int r = f >> 6, cc = f & 63;
            Bs[r][cc] = B[(size_t)(kk + r) * Nc + bn0 + cc];
        }
        __syncthreads();

        #pragma unroll
        for (int k = 0; k < TK; ++k) {
            float a[4], b[4];
            #pragma unroll
            for (int i = 0; i < 4; ++i) a[i] = As[k][ty * 4 + i];
            #pragma unroll
            for (int j = 0; j < 4; ++j) b[j] = Bs[k][tx * 4 + j];
            #pragma unroll
            for (int i = 0; i < 4; ++i)
                #pragma unroll
                for (int j = 0; j < 4; ++j)
                    acc[i][j] += a[i] * b[j];
        }
        __syncthreads();
    }

    #pragma unroll
    for (int i = 0; i < 4; ++i) {
        int gr = bm0 + ty * 4 + i;
        if (gr >= M) continue;
        #pragma unroll
        for (int j = 0; j < 4; ++j) {
            int gc = bn0 + tx * 4 + j;
            C[(size_t)gr * Nc + gc] = acc[i][j] + bias[gc];
        }
    }
}

// =====================================================================
// Sampling kernel v2: 4 queries per 256-thread block.
// Phase 1: per (h,l,pt) task -- softmax weight * bilinear corner weights
//          + premultiplied flat indices (n, level, head offsets folded)
//          written to LDS once.  128 tasks/query, 512 tasks/block.
// Phase 2: 64 lanes/query = 8 heads x 8 float4-channel-groups; each lane
//          does 16 tasks x 4 guarded float4 gathers + FMA.
// LDS layout for phase-2 reads: slot = t*8 + h  (consecutive h -> 16B
// apart -> 8 distinct addresses span all 32 banks; 8 lanes per head
// broadcast -> conflict-free ds_read_b128).
// =====================================================================
#define QB 4

__global__ __launch_bounds__(256) void msda_sample_kernel(
    const float* __restrict__ vproj, const float* __restrict__ offs,
    const float* __restrict__ logits, const float* __restrict__ p,
    float* __restrict__ mid)
{
    __shared__ float s_logit[QB][128];
    __shared__ float s_off[QB][256];
    __shared__ float s_p[QB][8];
    __shared__ float s_mx[QB][HEADS];
    __shared__ float s_inv[QB][HEADS];
    __shared__ float s_w[QB][128 * 4];     // [slot][corner]
    __shared__ int   s_idx[QB][128 * 4];

    const int tid = threadIdx.x;
    const int bq0 = blockIdx.x * QB;

    // ---- stage per-query small tensors ----
    #pragma unroll
    for (int i = tid; i < QB * 128; i += 256) {
        int sub = i >> 7, j = i & 127;
        s_logit[sub][j] = logits[(size_t)(bq0 + sub) * 128 + j];
    }
    #pragma unroll
    for (int i = tid; i < QB * 256; i += 256) {
        int sub = i >> 8, j = i & 255;
        s_off[sub][j] = offs[(size_t)(bq0 + sub) * 256 + j];
    }
    if (tid < QB * 8) {
        int sub = tid >> 3, j = tid & 7;
        s_p[sub][j] = p[(size_t)(bq0 + sub) * 8 + j];
    }
    __syncthreads();

    // ---- softmax stats: one thread per (sub, head) ----
    if (tid < QB * HEADS) {
        int sub = tid >> 3, h = tid & 7;
        float mx = -1e30f;
        #pragma unroll
        for (int i = 0; i < 16; ++i) mx = fmaxf(mx, s_logit[sub][h * 16 + i]);
        float ssum = 0.0f;
        #pragma unroll
        for (int i = 0; i < 16; ++i) ssum += __expf(s_logit[sub][h * 16 + i] - mx);
        s_mx[sub][h] = mx;
        s_inv[sub][h] = 1.0f / ssum;
    }
    __syncthreads();

    // ---- phase 1: 512 tasks (sub, h, l, pt) ----
    #pragma unroll
    for (int tt = tid; tt < QB * 128; tt += 256) {
        const int sub = tt >> 7;
        const int j   = tt & 127;          // h*16 + l*4 + pt
        const int h   = j >> 4;
        const int l   = (j >> 2) & 3;
        const int pt  = j & 3;
        const int nq  = bq0 + sub;
        const int nb  = (nq >= QN) ? 1 : 0;

        const int Hl = c_Hl[l], Wl = c_Wl[l], st = c_start[l];
        const float fW = (float)Wl, fH = (float)Hl;

        const float w = __expf(s_logit[sub][j] - s_mx[sub][h]) * s_inv[sub][h];

        const int oi = j * 2;
        const float ox = s_off[sub][oi];
        const float oy = s_off[sub][oi + 1];
        const float px = s_p[sub][l * 2 + 0];
        const float py = s_p[sub][l * 2 + 1];

        // mirror reference arithmetic exactly
        const float lx = px + ox / fW;
        const float ly = py + oy / fH;
        const float x = lx * fW - 0.5f;
        const float y = ly * fH - 0.5f;

        const float x0f = floorf(x), y0f = floorf(y);
        const int x0 = (int)x0f, y0 = (int)y0f;
        const float dx = x - x0f, dy = y - y0f;

        const int base = nb * (HW_TOT * DIMS) + h * CH;  // fold n & head offsets
        const int slot = ((j & 15) * 8 + h) * 4;         // [t][h] layout

        const bool vx0 = (x0 >= 0) & (x0 < Wl);
        const bool vx1 = (x0 + 1 >= 0) & (x0 + 1 < Wl);
        const bool vy0 = (y0 >= 0) & (y0 < Hl);
        const bool vy1 = (y0 + 1 >= 0) & (y0 + 1 < Hl);

        s_w[sub][slot + 0] = w * (1.0f - dx) * (1.0f - dy);
        s_w[sub][slot + 1] = w * dx * (1.0f - dy);
        s_w[sub][slot + 2] = w * (1.0f - dx) * dy;
        s_w[sub][slot + 3] = w * dx * dy;
        s_idx[sub][slot + 0] = (vx0 & vy0) ? base + (st + y0 * Wl + x0) * DIMS : -1;
        s_idx[sub][slot + 1] = (vx1 & vy0) ? base + (st + y0 * Wl + x0 + 1) * DIMS : -1;
        s_idx[sub][slot + 2] = (vx0 & vy1) ? base + ((y0 + 1) * Wl + x0 + st) * DIMS : -1;
        s_idx[sub][slot + 3] = (vx1 & vy1) ? base + ((y0 + 1) * Wl + x0 + 1 + st) * DIMS : -1;
    }
    __syncthreads();

    // ---- phase 2: gather + weighted accumulate, float4 per lane ----
    const int sub  = tid >> 6;
    const int lane = tid & 63;
    const int h    = lane >> 3;
    const int c4   = lane & 7;
    const int nq   = bq0 + sub;

    float ax = 0.0f, ay = 0.0f, az = 0.0f, aw = 0.0f;
    const float* __restrict__ vb = vproj + c4 * 4;

    #pragma unroll
    for (int t = 0; t < 16; ++t) {
        const int slot = (t * 8 + h) * 4;
        const int4   I = *(const int4*)&s_idx[sub][slot];
        const float4 W = *(const float4*)&s_w[sub][slot];

        if (I.x >= 0) {
            const float4 v = *(const float4*)(vb + I.x);
            ax = fmaf(W.x, v.x, ax); ay = fmaf(W.x, v.y, ay);
            az = fmaf(W.x, v.z, az); aw = fmaf(W.x, v.w, aw);
        }
        if (I.y >= 0) {
            const float4 v = *(const float4*)(vb + I.y);
            ax = fmaf(W.y, v.x, ax); ay = fmaf(W.y, v.y, ay);
            az = fmaf(W.y, v.z, az); aw = fmaf(W.y, v.w, aw);
        }
        if (I.z >= 0) {
            const float4 v = *(const float4*)(vb + I.z);
            ax = fmaf(W.z, v.x, ax); ay = fmaf(W.z, v.y, ay);
            az = fmaf(W.z, v.z, az); aw = fmaf(W.z, v.w, aw);
        }
        if (I.w >= 0) {
            const float4 v = *(const float4*)(vb + I.w);
            ax = fmaf(W.w, v.x, ax); ay = fmaf(W.w, v.y, ay);
            az = fmaf(W.w, v.z, az); aw = fmaf(W.w, v.w, aw);
        }
    }

    float4 r; r.x = ax; r.y = ay; r.z = az; r.w = aw;
    *(float4*)&mid[(size_t)nq * DIMS + lane * 4] = r;
}

// =====================================================================
extern "C" void kernel_launch(void* const* d_in, const int* in_sizes, int n_in,
                              void* d_out, int out_size, void* d_ws, size_t ws_size,
                              hipStream_t stream)
{
    const float* q      = (const float*)d_in[0];
    const float* p      = (const float*)d_in[1];
    const float* v      = (const float*)d_in[2];
    const float* W_off  = (const float*)d_in[3];
    const float* b_off  = (const float*)d_in[4];
    const float* W_attn = (const float*)d_in[5];
    const float* b_attn = (const float*)d_in[6];
    const float* W_in   = (const float*)d_in[7];
    const float* b_in   = (const float*)d_in[8];
    const float* W_out  = (const float*)d_in[9];
    const float* b_out  = (const float*)d_in[10];
    float* out = (float*)d_out;

    const int M = NB * QN;                         // 24480

    // workspace layout (floats)
    float* vproj  = (float*)d_ws;                  // N*HW*256
    float* offs   = vproj + (size_t)NB * HW_TOT * DIMS;
    float* logit  = offs  + (size_t)NB * QN * DIMS;      // N*Q*128
    float* mid    = logit + (size_t)NB * QN * 128;       // N*Q*256

    const int gx = (M + TM - 1) / TM;              // 383

    // 1) v_proj = v @ W_in + b_in
    sgemm_bias_kernel<<<dim3(gx, DIMS / TN), 256, 0, stream>>>(
        v, W_in, b_in, vproj, M, DIMS, DIMS);
    // 2) offsets = q @ W_off + b_off
    sgemm_bias_kernel<<<dim3(gx, DIMS / TN), 256, 0, stream>>>(
        q, W_off, b_off, offs, M, DIMS, DIMS);
    // 3) attn logits = q @ W_attn + b_attn
    sgemm_bias_kernel<<<dim3(gx, 128 / TN), 256, 0, stream>>>(
        q, W_attn, b_attn, logit, M, 128, DIMS);
    // 4) softmax + bilinear sampling + attention-weighted sum
    msda_sample_kernel<<<dim3(M / QB), 256, 0, stream>>>(vproj, offs, logit, p, mid);
    // 5) out = mid @ W_out + b_out
    sgemm_bias_kernel<<<dim3(gx, DIMS / TN), 256, 0, stream>>>(
        mid, W_out, b_out, out, M, DIMS, DIMS);
}

// Round 3
// 263.733 us; speedup vs baseline: 2.2772x; 1.5939x over previous
//
#include <hip/hip_runtime.h>
#include <hip/hip_bf16.h>
#include <math.h>

// ---- problem constants (structural, from the reference) ----
#define NB      2
#define QN      12240            // Q == HW
#define HW_TOT  12240
#define DIMS    256
#define HEADS   8
#define CH      32
#define LEVELS  4
#define POINTS  4

typedef unsigned short ushort_t;
typedef __attribute__((ext_vector_type(8))) short short8;
typedef __attribute__((ext_vector_type(4))) float floatx4;

__device__ __constant__ int c_Hl[4]    = {96, 48, 24, 12};
__device__ __constant__ int c_Wl[4]    = {96, 48, 24, 12};
__device__ __constant__ int c_start[4] = {0, 9216, 11520, 12096};

__device__ __forceinline__ ushort_t f2bf(float f) {
    __hip_bfloat16 h = __float2bfloat16(f);
    return *reinterpret_cast<ushort_t*>(&h);
}

// =====================================================================
// Weight transpose+convert: WT[n][k] = bf16(W[k][n]).  K=256 rows.
// z selects which weight; tiny (all weights ~768 KB total, L2-resident).
// =====================================================================
__global__ __launch_bounds__(256) void transpose_weights_kernel(
    const float* __restrict__ W0, const float* __restrict__ W1,
    const float* __restrict__ W2, const float* __restrict__ W3,
    ushort_t* __restrict__ T0, ushort_t* __restrict__ T1,
    ushort_t* __restrict__ T2, ushort_t* __restrict__ T3)
{
    const int z = blockIdx.z;
    const float* W; ushort_t* T; int Nw;
    if      (z == 0) { W = W0; T = T0; Nw = 256; }   // W_in
    else if (z == 1) { W = W1; T = T1; Nw = 256; }   // W_off
    else if (z == 2) { W = W2; T = T2; Nw = 128; }   // W_attn
    else             { W = W3; T = T3; Nw = 256; }   // W_out
    const int i = blockIdx.x * 256 + threadIdx.x;
    if (i >= Nw * 256) return;
    const int k = i & 255;        // coalesced write along k
    const int n = i >> 8;
    T[n * 256 + k] = f2bf(W[k * Nw + n]);
}

// =====================================================================
// bf16 MFMA GEMM: C[M,Nc] = A[M,K] @ BT[Nc,K]^T + bias, fp32 accum/out.
// 128x128 tile, BK=32, 256 threads = 4 waves in 2x2, each wave 64x64
// via 4x4 grid of v_mfma_f32_16x16x32_bf16.
// A is fp32 (converted during staging) when ABF16=false, bf16 otherwise.
// LDS rows padded to 40 bf16 (80 B = 16B-aligned, banks cycle period 8).
// =====================================================================
#define LDK 40

template<bool ABF16>
__global__ __launch_bounds__(256) void gemm_mfma_kernel(
    const void* __restrict__ Aptr, const ushort_t* __restrict__ BT,
    const float* __restrict__ bias, float* __restrict__ C,
    int M, int Nc, int K)
{
    __shared__ ushort_t As[128 * LDK];
    __shared__ ushort_t Bs[128 * LDK];

    const int tid  = threadIdx.x;
    const int wave = tid >> 6;
    const int lane = tid & 63;
    const int quad = lane >> 4;
    const int l16  = lane & 15;
    const int wm   = (wave >> 1) * 64;
    const int wn   = (wave & 1) * 64;
    const int bm0  = blockIdx.x * 128;
    const int bn0  = blockIdx.y * 128;

    floatx4 acc[4][4];
    #pragma unroll
    for (int i = 0; i < 4; ++i)
        #pragma unroll
        for (int j = 0; j < 4; ++j)
            acc[i][j] = (floatx4){0.f, 0.f, 0.f, 0.f};

    for (int kk = 0; kk < K; kk += 32) {
        // ---- stage A (128 rows x 32 k) ----
        if (ABF16) {
            const ushort_t* A = (const ushort_t*)Aptr;
            #pragma unroll
            for (int u = 0; u < 2; ++u) {
                int idx = tid + u * 256;        // unit = 8 bf16
                int r = idx >> 2, kc = (idx & 3) * 8;
                int gr = bm0 + r;
                int4 val = {0, 0, 0, 0};
                if (gr < M) val = *(const int4*)&A[(size_t)gr * K + kk + kc];
                *(int4*)&As[r * LDK + kc] = val;
            }
        } else {
            const float* A = (const float*)Aptr;
            #pragma unroll
            for (int u = 0; u < 4; ++u) {
                int idx = tid + u * 256;        // unit = 4 floats
                int r = idx >> 3, kc = (idx & 7) * 4;
                int gr = bm0 + r;
                float4 val = {0.f, 0.f, 0.f, 0.f};
                if (gr < M) val = *(const float4*)&A[(size_t)gr * K + kk + kc];
                ushort_t tmp[4] = {f2bf(val.x), f2bf(val.y), f2bf(val.z), f2bf(val.w)};
                *(uint2*)&As[r * LDK + kc] = *(uint2*)tmp;
            }
        }
        // ---- stage B from BT[n][k] (128 n-rows x 32 k) ----
        #pragma unroll
        for (int u = 0; u < 2; ++u) {
            int idx = tid + u * 256;            // unit = 8 bf16
            int n = idx >> 2, kc = (idx & 3) * 8;
            *(int4*)&Bs[n * LDK + kc] =
                *(const int4*)&BT[(size_t)(bn0 + n) * K + kk + kc];
        }
        __syncthreads();

        short8 af[4], bf[4];
        #pragma unroll
        for (int mt = 0; mt < 4; ++mt)
            af[mt] = *(const short8*)&As[(wm + mt * 16 + l16) * LDK + quad * 8];
        #pragma unroll
        for (int nt = 0; nt < 4; ++nt)
            bf[nt] = *(const short8*)&Bs[(wn + nt * 16 + l16) * LDK + quad * 8];
        #pragma unroll
        for (int mt = 0; mt < 4; ++mt)
            #pragma unroll
            for (int nt = 0; nt < 4; ++nt)
                acc[mt][nt] = __builtin_amdgcn_mfma_f32_16x16x32_bf16(
                    af[mt], bf[nt], acc[mt][nt], 0, 0, 0);
        __syncthreads();
    }

    // ---- epilogue: D row = wm+mt*16+quad*4+j, col = wn+nt*16+l16 ----
    #pragma unroll
    for (int mt = 0; mt < 4; ++mt) {
        #pragma unroll
        for (int j = 0; j < 4; ++j) {
            int row = bm0 + wm + mt * 16 + quad * 4 + j;
            if (row >= M) continue;
            #pragma unroll
            for (int nt = 0; nt < 4; ++nt) {
                int col = bn0 + wn + nt * 16 + l16;
                C[(size_t)row * Nc + col] = acc[mt][nt][j] + bias[col];
            }
        }
    }
}

// =====================================================================
// Sampling kernel v3: 4 queries per 256-thread block.
// Phase 1: per (h,l,pt) task, softmax*bilinear weights + flat idx -> LDS.
//   slot = t*36 + h*4 floats: phase-1 16B writes cycle banks (2-way max),
//   phase-2 int4 reads span all 32 banks.
// Phase 2: 64 lanes/query = 8 heads x 8 float4 groups, unconditional
//   gathers (invalid corner -> idx 0, weight 0).  Writes mid as bf16.
// =====================================================================
#define QB 4
#define SLOTS 576    // 15*36 + 7*4 + 4 = 572, padded to 16B multiple

__global__ __launch_bounds__(256) void msda_sample_kernel(
    const float* __restrict__ vproj, const float* __restrict__ offs,
    const float* __restrict__ logits, const float* __restrict__ p,
    ushort_t* __restrict__ mid)
{
    __shared__ float s_logit[QB][128];
    __shared__ float s_off[QB][256];
    __shared__ float s_p[QB][8];
    __shared__ float s_mx[QB][HEADS];
    __shared__ float s_inv[QB][HEADS];
    __shared__ float s_w[QB][SLOTS];
    __shared__ int   s_idx[QB][SLOTS];

    const int tid = threadIdx.x;
    const int bq0 = blockIdx.x * QB;

    #pragma unroll
    for (int i = tid; i < QB * 128; i += 256) {
        int sub = i >> 7, j = i & 127;
        s_logit[sub][j] = logits[(size_t)(bq0 + sub) * 128 + j];
    }
    #pragma unroll
    for (int i = tid; i < QB * 256; i += 256) {
        int sub = i >> 8, j = i & 255;
        s_off[sub][j] = offs[(size_t)(bq0 + sub) * 256 + j];
    }
    if (tid < QB * 8) {
        int sub = tid >> 3, j = tid & 7;
        s_p[sub][j] = p[(size_t)(bq0 + sub) * 8 + j];
    }
    __syncthreads();

    if (tid < QB * HEADS) {
        int sub = tid >> 3, h = tid & 7;
        float mx = -1e30f;
        #pragma unroll
        for (int i = 0; i < 16; ++i) mx = fmaxf(mx, s_logit[sub][h * 16 + i]);
        float ssum = 0.0f;
        #pragma unroll
        for (int i = 0; i < 16; ++i) ssum += __expf(s_logit[sub][h * 16 + i] - mx);
        s_mx[sub][h] = mx;
        s_inv[sub][h] = 1.0f / ssum;
    }
    __syncthreads();

    // ---- phase 1: 512 tasks (sub, h, l, pt) ----
    #pragma unroll
    for (int tt = tid; tt < QB * 128; tt += 256) {
        const int sub = tt >> 7;
        const int j   = tt & 127;          // h*16 + l*4 + pt
        const int h   = j >> 4;
        const int l   = (j >> 2) & 3;
        const int nq  = bq0 + sub;
        const int nb  = (nq >= QN) ? 1 : 0;

        const int Hl = c_Hl[l], Wl = c_Wl[l], st = c_start[l];
        const float fW = (float)Wl, fH = (float)Hl;

        const float w = __expf(s_logit[sub][j] - s_mx[sub][h]) * s_inv[sub][h];

        const int oi = j * 2;
        const float ox = s_off[sub][oi];
        const float oy = s_off[sub][oi + 1];
        const float px = s_p[sub][l * 2 + 0];
        const float py = s_p[sub][l * 2 + 1];

        // mirror reference arithmetic exactly
        const float lx = px + ox / fW;
        const float ly = py + oy / fH;
        const float x = lx * fW - 0.5f;
        const float y = ly * fH - 0.5f;

        const float x0f = floorf(x), y0f = floorf(y);
        const int x0 = (int)x0f, y0 = (int)y0f;
        const float dx = x - x0f, dy = y - y0f;

        const int base = nb * (HW_TOT * DIMS) + h * CH;
        const int slot = (j & 15) * 36 + h * 4;

        const bool vx0 = (x0 >= 0) & (x0 < Wl);
        const bool vx1 = (x0 + 1 >= 0) & (x0 + 1 < Wl);
        const bool vy0 = (y0 >= 0) & (y0 < Hl);
        const bool vy1 = (y0 + 1 >= 0) & (y0 + 1 < Hl);

        s_w[sub][slot + 0] = (vx0 & vy0) ? w * (1.0f - dx) * (1.0f - dy) : 0.0f;
        s_w[sub][slot + 1] = (vx1 & vy0) ? w * dx * (1.0f - dy) : 0.0f;
        s_w[sub][slot + 2] = (vx0 & vy1) ? w * (1.0f - dx) * dy : 0.0f;
        s_w[sub][slot + 3] = (vx1 & vy1) ? w * dx * dy : 0.0f;
        s_idx[sub][slot + 0] = (vx0 & vy0) ? base + (st + y0 * Wl + x0) * DIMS : 0;
        s_idx[sub][slot + 1] = (vx1 & vy0) ? base + (st + y0 * Wl + x0 + 1) * DIMS : 0;
        s_idx[sub][slot + 2] = (vx0 & vy1) ? base + (st + (y0 + 1) * Wl + x0) * DIMS : 0;
        s_idx[sub][slot + 3] = (vx1 & vy1) ? base + (st + (y0 + 1) * Wl + x0 + 1) * DIMS : 0;
    }
    __syncthreads();

    // ---- phase 2: unconditional gathers, float4 per lane ----
    const int sub  = tid >> 6;
    const int lane = tid & 63;
    const int h    = lane >> 3;
    const int c4   = lane & 7;
    const int nq   = bq0 + sub;

    float ax = 0.0f, ay = 0.0f, az = 0.0f, aw = 0.0f;
    const float* __restrict__ vb = vproj + c4 * 4;

    #pragma unroll
    for (int t = 0; t < 16; ++t) {
        const int slot = t * 36 + h * 4;
        const int4   I = *(const int4*)&s_idx[sub][slot];
        const float4 W = *(const float4*)&s_w[sub][slot];

        const float4 v0 = *(const float4*)(vb + I.x);
        const float4 v1 = *(const float4*)(vb + I.y);
        const float4 v2 = *(const float4*)(vb + I.z);
        const float4 v3 = *(const float4*)(vb + I.w);

        ax = fmaf(W.x, v0.x, ax); ay = fmaf(W.x, v0.y, ay);
        az = fmaf(W.x, v0.z, az); aw = fmaf(W.x, v0.w, aw);
        ax = fmaf(W.y, v1.x, ax); ay = fmaf(W.y, v1.y, ay);
        az = fmaf(W.y, v1.z, az); aw = fmaf(W.y, v1.w, aw);
        ax = fmaf(W.z, v2.x, ax); ay = fmaf(W.z, v2.y, ay);
        az = fmaf(W.z, v2.z, az); aw = fmaf(W.z, v2.w, aw);
        ax = fmaf(W.w, v3.x, ax); ay = fmaf(W.w, v3.y, ay);
        az = fmaf(W.w, v3.z, az); aw = fmaf(W.w, v3.w, aw);
    }

    ushort_t mv[4] = {f2bf(ax), f2bf(ay), f2bf(az), f2bf(aw)};
    *(uint2*)&mid[(size_t)nq * DIMS + lane * 4] = *(uint2*)mv;
}

// =====================================================================
extern "C" void kernel_launch(void* const* d_in, const int* in_sizes, int n_in,
                              void* d_out, int out_size, void* d_ws, size_t ws_size,
                              hipStream_t stream)
{
    const float* q      = (const float*)d_in[0];
    const float* p      = (const float*)d_in[1];
    const float* v      = (const float*)d_in[2];
    const float* W_off  = (const float*)d_in[3];
    const float* b_off  = (const float*)d_in[4];
    const float* W_attn = (const float*)d_in[5];
    const float* b_attn = (const float*)d_in[6];
    const float* W_in   = (const float*)d_in[7];
    const float* b_in   = (const float*)d_in[8];
    const float* W_out  = (const float*)d_in[9];
    const float* b_out  = (const float*)d_in[10];
    float* out = (float*)d_out;

    const int M = NB * QN;                         // 24480

    // workspace layout
    float* vproj  = (float*)d_ws;                               // 25.07 MB
    float* offs   = vproj + (size_t)NB * HW_TOT * DIMS;         // 25.07 MB
    float* logit  = offs  + (size_t)NB * QN * DIMS;             // 12.53 MB
    ushort_t* mid = (ushort_t*)(logit + (size_t)NB * QN * 128); // 12.53 MB
    ushort_t* Tin  = mid  + (size_t)M * DIMS;                   // bf16 weights
    ushort_t* Toff = Tin  + 256 * 256;
    ushort_t* Tattn= Toff + 256 * 256;
    ushort_t* Tout = Tattn + 128 * 256;

    // 0) weights -> transposed bf16
    transpose_weights_kernel<<<dim3(256, 1, 4), 256, 0, stream>>>(
        W_in, W_off, W_attn, W_out, Tin, Toff, Tattn, Tout);

    const dim3 g256((M + 127) / 128, 2), g128((M + 127) / 128, 1);

    // 1) v_proj = v @ W_in + b_in       (fp32 out for fp32 sampling)
    gemm_mfma_kernel<false><<<g256, 256, 0, stream>>>(v, Tin, b_in, vproj, M, 256, 256);
    // 2) offsets = q @ W_off + b_off
    gemm_mfma_kernel<false><<<g256, 256, 0, stream>>>(q, Toff, b_off, offs, M, 256, 256);
    // 3) attn logits = q @ W_attn + b_attn
    gemm_mfma_kernel<false><<<g128, 256, 0, stream>>>(q, Tattn, b_attn, logit, M, 128, 256);
    // 4) softmax + bilinear sampling + attention-weighted sum -> bf16 mid
    msda_sample_kernel<<<dim3(M / QB), 256, 0, stream>>>(vproj, offs, logit, p, mid);
    // 5) out = mid @ W_out + b_out
    gemm_mfma_kernel<true><<<g256, 256, 0, stream>>>(mid, Tout, b_out, out, M, 256, 256);
}

// Round 4
// 218.507 us; speedup vs baseline: 2.7485x; 1.2070x over previous
//
#include <hip/hip_runtime.h>
#include <hip/hip_bf16.h>
#include <math.h>

// ---- problem constants (structural, from the reference) ----
#define NB      2
#define QN      12240
#define HW_TOT  12240
#define DIMS    256
#define HEADS   8
#define CH      32
#define LEVELS  4
#define POINTS  4
#define M_TOT   (NB * QN)        // 24480

typedef unsigned short ushort_t;
typedef __attribute__((ext_vector_type(8))) short short8;
typedef __attribute__((ext_vector_type(4))) float floatx4;

__device__ __constant__ int c_Hl[4]    = {96, 48, 24, 12};
__device__ __constant__ int c_Wl[4]    = {96, 48, 24, 12};
__device__ __constant__ int c_start[4] = {0, 9216, 11520, 12096};

__device__ __forceinline__ ushort_t f2bf(float f) {
    __hip_bfloat16 h = __float2bfloat16(f);
    return *reinterpret_cast<ushort_t*>(&h);
}

// =====================================================================
// Elementwise fp32 -> bf16 for v and q (one pass, 8 elems/thread).
// =====================================================================
__global__ __launch_bounds__(256) void convert_qv_kernel(
    const float* __restrict__ v, const float* __restrict__ q,
    ushort_t* __restrict__ vbf, ushort_t* __restrict__ qbf)
{
    const size_t i = ((size_t)blockIdx.x * 256 + threadIdx.x) * 8;
    const size_t half = (size_t)M_TOT * DIMS;
    const float* src; ushort_t* dst; size_t off;
    if (i < half) { src = v; dst = vbf; off = i; }
    else          { src = q; dst = qbf; off = i - half; }
    const float4 a = *(const float4*)&src[off];
    const float4 b = *(const float4*)&src[off + 4];
    ushort_t t[8] = {f2bf(a.x), f2bf(a.y), f2bf(a.z), f2bf(a.w),
                     f2bf(b.x), f2bf(b.y), f2bf(b.z), f2bf(b.w)};
    *(int4*)&dst[off] = *(int4*)t;
}

// =====================================================================
// Weights -> transposed bf16 (WT[n][k]); z=1 also builds the fused
// off+attn weight [384][256] and its combined bias.
// =====================================================================
__global__ __launch_bounds__(256) void prep_weights_kernel(
    const float* __restrict__ W_in, const float* __restrict__ W_off,
    const float* __restrict__ W_attn, const float* __restrict__ W_out,
    const float* __restrict__ b_off, const float* __restrict__ b_attn,
    ushort_t* __restrict__ Tin, ushort_t* __restrict__ Tcomb,
    ushort_t* __restrict__ Tout, float* __restrict__ bcomb)
{
    const int z  = blockIdx.z;
    const int gi = blockIdx.x * 256 + threadIdx.x;
    if (z == 1 && gi < 384)
        bcomb[gi] = (gi < 256) ? b_off[gi] : b_attn[gi - 256];
    const int Nw = (z == 1) ? 384 : 256;
    if (gi >= Nw * 256) return;
    const int k = gi & 255;       // coalesced write along k
    const int n = gi >> 8;
    float val; ushort_t* T;
    if (z == 0)      { val = W_in[k * 256 + n];  T = Tin;  }
    else if (z == 1) { val = (n < 256) ? W_off[k * 256 + n]
                                       : W_attn[k * 128 + (n - 256)]; T = Tcomb; }
    else             { val = W_out[k * 256 + n]; T = Tout; }
    T[n * 256 + k] = f2bf(val);
}

// =====================================================================
// bf16 MFMA GEMM: C[M,Nc] = A[M,K] @ BT[Nc,K]^T + bias.
// 128x64 tile, BK=32, 256 threads = 4 waves (2x2), wave = 64x32 via
// 4x2 grid of v_mfma_f32_16x16x32_bf16.  A & BT are bf16 (pure int4
// staging, no conversion in the K-loop).  LDS 12 KB -> high occupancy.
// OutT: float or ushort_t(bf16).
// =====================================================================
__device__ __forceinline__ void storeval(float* C, size_t i, float v)    { C[i] = v; }
__device__ __forceinline__ void storeval(ushort_t* C, size_t i, float v) { C[i] = f2bf(v); }

template<typename OutT>
__global__ __launch_bounds__(256) void gemm_bf16_kernel(
    const ushort_t* __restrict__ A, const ushort_t* __restrict__ BT,
    const float* __restrict__ bias, OutT* __restrict__ C,
    int M, int Nc, int K)
{
    __shared__ ushort_t As[128 * 32];
    __shared__ ushort_t Bs[64 * 32];

    const int tid  = threadIdx.x;
    const int wave = tid >> 6;
    const int lane = tid & 63;
    const int quad = lane >> 4;
    const int l16  = lane & 15;
    const int wm   = (wave >> 1) * 64;
    const int wn   = (wave & 1) * 32;
    const int bm0  = blockIdx.x * 128;
    const int bn0  = blockIdx.y * 64;

    const int arow = tid >> 2;          // 0..63 (A rows +0 / +64; B n-row)
    const int akc  = (tid & 3) * 8;     // 8 bf16 = 16 B per thread-chunk

    floatx4 acc[4][2];
    #pragma unroll
    for (int i = 0; i < 4; ++i)
        #pragma unroll
        for (int j = 0; j < 2; ++j)
            acc[i][j] = (floatx4){0.f, 0.f, 0.f, 0.f};

    int ga0 = bm0 + arow;      if (ga0 > M - 1) ga0 = M - 1;
    int ga1 = bm0 + arow + 64; if (ga1 > M - 1) ga1 = M - 1;

    for (int kk = 0; kk < K; kk += 32) {
        const int4 va0 = *(const int4*)&A[(size_t)ga0 * K + kk + akc];
        const int4 va1 = *(const int4*)&A[(size_t)ga1 * K + kk + akc];
        const int4 vb  = *(const int4*)&BT[(size_t)(bn0 + arow) * K + kk + akc];
        *(int4*)&As[arow * 32 + akc]        = va0;
        *(int4*)&As[(arow + 64) * 32 + akc] = va1;
        *(int4*)&Bs[arow * 32 + akc]        = vb;
        __syncthreads();

        short8 af[4], bfr[2];
        #pragma unroll
        for (int mt = 0; mt < 4; ++mt)
            af[mt] = *(const short8*)&As[(wm + mt * 16 + l16) * 32 + quad * 8];
        #pragma unroll
        for (int nt = 0; nt < 2; ++nt)
            bfr[nt] = *(const short8*)&Bs[(wn + nt * 16 + l16) * 32 + quad * 8];
        #pragma unroll
        for (int mt = 0; mt < 4; ++mt)
            #pragma unroll
            for (int nt = 0; nt < 2; ++nt)
                acc[mt][nt] = __builtin_amdgcn_mfma_f32_16x16x32_bf16(
                    af[mt], bfr[nt], acc[mt][nt], 0, 0, 0);
        __syncthreads();
    }

    #pragma unroll
    for (int mt = 0; mt < 4; ++mt) {
        #pragma unroll
        for (int j = 0; j < 4; ++j) {
            const int row = bm0 + wm + mt * 16 + quad * 4 + j;
            if (row >= M) continue;
            #pragma unroll
            for (int nt = 0; nt < 2; ++nt) {
                const int col = bn0 + wn + nt * 16 + l16;
                storeval(C, (size_t)row * Nc + col, acc[mt][nt][j] + bias[col]);
            }
        }
    }
}

// =====================================================================
// Sampling kernel v4: 4 queries/block; bf16 vproj gathers (8 B/lane).
// Phase 1 as v3 (slot stride 36 floats, conflict-cycling).
// offlog holds [offsets(256) | logits(128)] fused, stride 384.
// =====================================================================
#define QB 4
#define SLOTS 576

__global__ __launch_bounds__(256) void msda_sample_kernel(
    const ushort_t* __restrict__ vproj, const float* __restrict__ offlog,
    const float* __restrict__ p, ushort_t* __restrict__ mid)
{
    __shared__ float s_logit[QB][128];
    __shared__ float s_off[QB][256];
    __shared__ float s_p[QB][8];
    __shared__ float s_mx[QB][HEADS];
    __shared__ float s_inv[QB][HEADS];
    __shared__ float s_w[QB][SLOTS];
    __shared__ int   s_idx[QB][SLOTS];

    const int tid = threadIdx.x;
    const int bq0 = blockIdx.x * QB;

    #pragma unroll
    for (int i = tid; i < QB * 256; i += 256) {
        int sub = i >> 8, j = i & 255;
        s_off[sub][j] = offlog[(size_t)(bq0 + sub) * 384 + j];
    }
    #pragma unroll
    for (int i = tid; i < QB * 128; i += 256) {
        int sub = i >> 7, j = i & 127;
        s_logit[sub][j] = offlog[(size_t)(bq0 + sub) * 384 + 256 + j];
    }
    if (tid < QB * 8) {
        int sub = tid >> 3, j = tid & 7;
        s_p[sub][j] = p[(size_t)(bq0 + sub) * 8 + j];
    }
    __syncthreads();

    if (tid < QB * HEADS) {
        int sub = tid >> 3, h = tid & 7;
        float mx = -1e30f;
        #pragma unroll
        for (int i = 0; i < 16; ++i) mx = fmaxf(mx, s_logit[sub][h * 16 + i]);
        float ssum = 0.0f;
        #pragma unroll
        for (int i = 0; i < 16; ++i) ssum += __expf(s_logit[sub][h * 16 + i] - mx);
        s_mx[sub][h] = mx;
        s_inv[sub][h] = 1.0f / ssum;
    }
    __syncthreads();

    // ---- phase 1: 512 tasks (sub, h, l, pt) ----
    #pragma unroll
    for (int tt = tid; tt < QB * 128; tt += 256) {
        const int sub = tt >> 7;
        const int j   = tt & 127;          // h*16 + l*4 + pt
        const int h   = j >> 4;
        const int l   = (j >> 2) & 3;
        const int nq  = bq0 + sub;
        const int nb  = (nq >= QN) ? 1 : 0;

        const int Hl = c_Hl[l], Wl = c_Wl[l], st = c_start[l];
        const float fW = (float)Wl, fH = (float)Hl;

        const float w = __expf(s_logit[sub][j] - s_mx[sub][h]) * s_inv[sub][h];

        const int oi = j * 2;
        const float ox = s_off[sub][oi];
        const float oy = s_off[sub][oi + 1];
        const float px = s_p[sub][l * 2 + 0];
        const float py = s_p[sub][l * 2 + 1];

        const float lx = px + ox / fW;
        const float ly = py + oy / fH;
        const float x = lx * fW - 0.5f;
        const float y = ly * fH - 0.5f;

        const float x0f = floorf(x), y0f = floorf(y);
        const int x0 = (int)x0f, y0 = (int)y0f;
        const float dx = x - x0f, dy = y - y0f;

        const int base = nb * (HW_TOT * DIMS) + h * CH;
        const int slot = (j & 15) * 36 + h * 4;

        const bool vx0 = (x0 >= 0) & (x0 < Wl);
        const bool vx1 = (x0 + 1 >= 0) & (x0 + 1 < Wl);
        const bool vy0 = (y0 >= 0) & (y0 < Hl);
        const bool vy1 = (y0 + 1 >= 0) & (y0 + 1 < Hl);

        s_w[sub][slot + 0] = (vx0 & vy0) ? w * (1.0f - dx) * (1.0f - dy) : 0.0f;
        s_w[sub][slot + 1] = (vx1 & vy0) ? w * dx * (1.0f - dy) : 0.0f;
        s_w[sub][slot + 2] = (vx0 & vy1) ? w * (1.0f - dx) * dy : 0.0f;
        s_w[sub][slot + 3] = (vx1 & vy1) ? w * dx * dy : 0.0f;
        s_idx[sub][slot + 0] = (vx0 & vy0) ? base + (st + y0 * Wl + x0) * DIMS : 0;
        s_idx[sub][slot + 1] = (vx1 & vy0) ? base + (st + y0 * Wl + x0 + 1) * DIMS : 0;
        s_idx[sub][slot + 2] = (vx0 & vy1) ? base + (st + (y0 + 1) * Wl + x0) * DIMS : 0;
        s_idx[sub][slot + 3] = (vx1 & vy1) ? base + (st + (y0 + 1) * Wl + x0 + 1) * DIMS : 0;
    }
    __syncthreads();

    // ---- phase 2: bf16 gathers (uint2 = 4 channels), fp32 accumulate ----
    const int sub  = tid >> 6;
    const int lane = tid & 63;
    const int h    = lane >> 3;
    const int c4   = lane & 7;
    const int nq   = bq0 + sub;

    float ax = 0.0f, ay = 0.0f, az = 0.0f, aw = 0.0f;
    const ushort_t* __restrict__ vb = vproj + c4 * 4;

    #pragma unroll
    for (int t = 0; t < 16; ++t) {
        const int slot = t * 36 + h * 4;
        const int4   I = *(const int4*)&s_idx[sub][slot];
        const float4 W = *(const float4*)&s_w[sub][slot];

        const uint2 g0 = *(const uint2*)(vb + I.x);
        const uint2 g1 = *(const uint2*)(vb + I.y);
        const uint2 g2 = *(const uint2*)(vb + I.z);
        const uint2 g3 = *(const uint2*)(vb + I.w);

        ax = fmaf(W.x, __uint_as_float(g0.x << 16), ax);
        ay = fmaf(W.x, __uint_as_float(g0.x & 0xffff0000u), ay);
        az = fmaf(W.x, __uint_as_float(g0.y << 16), az);
        aw = fmaf(W.x, __uint_as_float(g0.y & 0xffff0000u), aw);

        ax = fmaf(W.y, __uint_as_float(g1.x << 16), ax);
        ay = fmaf(W.y, __uint_as_float(g1.x & 0xffff0000u), ay);
        az = fmaf(W.y, __uint_as_float(g1.y << 16), az);
        aw = fmaf(W.y, __uint_as_float(g1.y & 0xffff0000u), aw);

        ax = fmaf(W.z, __uint_as_float(g2.x << 16), ax);
        ay = fmaf(W.z, __uint_as_float(g2.x & 0xffff0000u), ay);
        az = fmaf(W.z, __uint_as_float(g2.y << 16), az);
        aw = fmaf(W.z, __uint_as_float(g2.y & 0xffff0000u), aw);

        ax = fmaf(W.w, __uint_as_float(g3.x << 16), ax);
        ay = fmaf(W.w, __uint_as_float(g3.x & 0xffff0000u), ay);
        az = fmaf(W.w, __uint_as_float(g3.y << 16), az);
        aw = fmaf(W.w, __uint_as_float(g3.y & 0xffff0000u), aw);
    }

    ushort_t mv[4] = {f2bf(ax), f2bf(ay), f2bf(az), f2bf(aw)};
    *(uint2*)&mid[(size_t)nq * DIMS + lane * 4] = *(uint2*)mv;
}

// =====================================================================
extern "C" void kernel_launch(void* const* d_in, const int* in_sizes, int n_in,
                              void* d_out, int out_size, void* d_ws, size_t ws_size,
                              hipStream_t stream)
{
    const float* q      = (const float*)d_in[0];
    const float* p      = (const float*)d_in[1];
    const float* v      = (const float*)d_in[2];
    const float* W_off  = (const float*)d_in[3];
    const float* b_off  = (const float*)d_in[4];
    const float* W_attn = (const float*)d_in[5];
    const float* b_attn = (const float*)d_in[6];
    const float* W_in   = (const float*)d_in[7];
    const float* b_in   = (const float*)d_in[8];
    const float* W_out  = (const float*)d_in[9];
    const float* b_out  = (const float*)d_in[10];
    float* out = (float*)d_out;

    const int M = M_TOT;                            // 24480

    // workspace layout (mid aliases vbf -- vbf dead after GEMM1)
    ushort_t* vproj  = (ushort_t*)d_ws;                          // M*256 bf16
    float*    offlog = (float*)(vproj + (size_t)M * 256);        // M*384 f32
    ushort_t* vbf    = (ushort_t*)(offlog + (size_t)M * 384);    // M*256 bf16
    ushort_t* mid    = vbf;                                      // alias
    ushort_t* qbf    = vbf + (size_t)M * 256;                    // M*256 bf16
    ushort_t* Tin    = qbf + (size_t)M * 256;
    ushort_t* Tcomb  = Tin + 256 * 256;
    ushort_t* Tout   = Tcomb + 384 * 256;
    float*    bcomb  = (float*)(Tout + 256 * 256);

    // 0a) v,q -> bf16
    convert_qv_kernel<<<dim3(6120), 256, 0, stream>>>(v, q, vbf, qbf);
    // 0b) weights -> transposed bf16 (+ fused off/attn weight & bias)
    prep_weights_kernel<<<dim3(384, 1, 3), 256, 0, stream>>>(
        W_in, W_off, W_attn, W_out, b_off, b_attn, Tin, Tcomb, Tout, bcomb);

    // 1) vproj = v @ W_in + b_in   (bf16 out)
    gemm_bf16_kernel<ushort_t><<<dim3(192, 4), 256, 0, stream>>>(
        vbf, Tin, b_in, vproj, M, 256, 256);
    // 2+3) offlog = q @ [W_off|W_attn] + [b_off|b_attn]   (fp32 out)
    gemm_bf16_kernel<float><<<dim3(192, 6), 256, 0, stream>>>(
        qbf, Tcomb, bcomb, offlog, M, 384, 256);
    // 4) softmax + bilinear sampling -> bf16 mid
    msda_sample_kernel<<<dim3(M / QB), 256, 0, stream>>>(vproj, offlog, p, mid);
    // 5) out = mid @ W_out + b_out
    gemm_bf16_kernel<float><<<dim3(192, 4), 256, 0, stream>>>(
        mid, Tout, b_out, out, M, 256, 256);
}

// Round 5
// 208.629 us; speedup vs baseline: 2.8787x; 1.0473x over previous
//
#include <hip/hip_runtime.h>
#include <hip/hip_bf16.h>
#include <math.h>

// ---- problem constants (structural, from the reference) ----
#define NB      2
#define QN      12240
#define HW_TOT  12240
#define DIMS    256
#define HEADS   8
#define CH      32
#define LEVELS  4
#define POINTS  4
#define M_TOT   (NB * QN)        // 24480

typedef unsigned short ushort_t;
typedef __attribute__((ext_vector_type(8))) short short8;
typedef __attribute__((ext_vector_type(4))) float floatx4;

__device__ __constant__ int c_Hl[4]    = {96, 48, 24, 12};
__device__ __constant__ int c_Wl[4]    = {96, 48, 24, 12};
__device__ __constant__ int c_start[4] = {0, 9216, 11520, 12096};

__device__ __forceinline__ ushort_t f2bf(float f) {
    __hip_bfloat16 h = __float2bfloat16(f);
    return *reinterpret_cast<ushort_t*>(&h);
}

// =====================================================================
// Elementwise fp32 -> bf16 for v and q (one pass, 8 elems/thread).
// =====================================================================
__global__ __launch_bounds__(256) void convert_qv_kernel(
    const float* __restrict__ v, const float* __restrict__ q,
    ushort_t* __restrict__ vbf, ushort_t* __restrict__ qbf)
{
    const size_t i = ((size_t)blockIdx.x * 256 + threadIdx.x) * 8;
    const size_t half = (size_t)M_TOT * DIMS;
    const float* src; ushort_t* dst; size_t off;
    if (i < half) { src = v; dst = vbf; off = i; }
    else          { src = q; dst = qbf; off = i - half; }
    const float4 a = *(const float4*)&src[off];
    const float4 b = *(const float4*)&src[off + 4];
    ushort_t t[8] = {f2bf(a.x), f2bf(a.y), f2bf(a.z), f2bf(a.w),
                     f2bf(b.x), f2bf(b.y), f2bf(b.z), f2bf(b.w)};
    *(int4*)&dst[off] = *(int4*)t;
}

// =====================================================================
// Weights -> transposed bf16 (WT[n][k]); z=1 also builds the fused
// off+attn weight [384][256] and its combined bias.
// =====================================================================
__global__ __launch_bounds__(256) void prep_weights_kernel(
    const float* __restrict__ W_in, const float* __restrict__ W_off,
    const float* __restrict__ W_attn, const float* __restrict__ W_out,
    const float* __restrict__ b_off, const float* __restrict__ b_attn,
    ushort_t* __restrict__ Tin, ushort_t* __restrict__ Tcomb,
    ushort_t* __restrict__ Tout, float* __restrict__ bcomb)
{
    const int z  = blockIdx.z;
    const int gi = blockIdx.x * 256 + threadIdx.x;
    if (z == 1 && gi < 384)
        bcomb[gi] = (gi < 256) ? b_off[gi] : b_attn[gi - 256];
    const int Nw = (z == 1) ? 384 : 256;
    if (gi >= Nw * 256) return;
    const int k = gi & 255;       // coalesced write along k
    const int n = gi >> 8;
    float val; ushort_t* T;
    if (z == 0)      { val = W_in[k * 256 + n];  T = Tin;  }
    else if (z == 1) { val = (n < 256) ? W_off[k * 256 + n]
                                       : W_attn[k * 128 + (n - 256)]; T = Tcomb; }
    else             { val = W_out[k * 256 + n]; T = Tout; }
    T[n * 256 + k] = f2bf(val);
}

// =====================================================================
// m97-style bf16 MFMA GEMM core: C[M,Nc] = A[M,K] @ BT[Nc,K]^T + bias.
// 128x128 tile, BK=32, 256 threads = 4 waves (2x2), wave = 64x64 via
// 4x4 grid of v_mfma_f32_16x16x32_bf16.  Staging via global_load_lds
// width=16 (wave-uniform LDS base + lane*16, contiguous row-major tile,
// NO padding -- m104 constraint).  M-tail: load rows clamped to M-1;
// garbage rows only affect C rows >= M which are never stored.
// =====================================================================
__device__ __forceinline__ void gemm_tile_core(
    const ushort_t* __restrict__ A, const ushort_t* __restrict__ BT,
    const float* __restrict__ bias, void* __restrict__ C, bool c_bf16,
    int M, int Nc, int bm0, int bn0, int K,
    ushort_t* As, ushort_t* Bs)
{
    const int tid  = threadIdx.x;
    const int wave = tid >> 6;
    const int lane = tid & 63;
    const int quad = lane >> 4;
    const int l16  = lane & 15;
    const int wm   = (wave >> 1) * 64;
    const int wn   = (wave & 1) * 64;

    // staging geometry: LDS byte off = tid*16 (+4096 round 1)
    const int off0 = tid * 16;
    const int row0 = off0 >> 6;           // 0..63 (tile row, 64B = 32 bf16/row)
    const int kc0  = (off0 & 63) >> 1;    // element k-offset: 0/8/16/24

    int ar0 = bm0 + row0;      if (ar0 > M - 1) ar0 = M - 1;
    int ar1 = bm0 + row0 + 64; if (ar1 > M - 1) ar1 = M - 1;

    const ushort_t* ga0 = A  + (size_t)ar0 * K + kc0;
    const ushort_t* ga1 = A  + (size_t)ar1 * K + kc0;
    const ushort_t* gb0 = BT + (size_t)(bn0 + row0) * K + kc0;
    const ushort_t* gb1 = BT + (size_t)(bn0 + row0 + 64) * K + kc0;

    // wave-uniform LDS bases (ushort units): wave*512, +2048 for round 1
    ushort_t* lA0 = As + wave * 512;
    ushort_t* lA1 = As + wave * 512 + 2048;
    ushort_t* lB0 = Bs + wave * 512;
    ushort_t* lB1 = Bs + wave * 512 + 2048;

    floatx4 acc[4][4];
    #pragma unroll
    for (int i = 0; i < 4; ++i)
        #pragma unroll
        for (int j = 0; j < 4; ++j)
            acc[i][j] = (floatx4){0.f, 0.f, 0.f, 0.f};

    for (int kk = 0; kk < K; kk += 32) {
        __builtin_amdgcn_global_load_lds(
            (const __attribute__((address_space(1))) void*)(ga0 + kk),
            (__attribute__((address_space(3))) void*)lA0, 16, 0, 0);
        __builtin_amdgcn_global_load_lds(
            (const __attribute__((address_space(1))) void*)(ga1 + kk),
            (__attribute__((address_space(3))) void*)lA1, 16, 0, 0);
        __builtin_amdgcn_global_load_lds(
            (const __attribute__((address_space(1))) void*)(gb0 + kk),
            (__attribute__((address_space(3))) void*)lB0, 16, 0, 0);
        __builtin_amdgcn_global_load_lds(
            (const __attribute__((address_space(1))) void*)(gb1 + kk),
            (__attribute__((address_space(3))) void*)lB1, 16, 0, 0);
        __syncthreads();

        short8 af[4], bfr[4];
        #pragma unroll
        for (int mt = 0; mt < 4; ++mt)
            af[mt] = *(const short8*)&As[(wm + mt * 16 + l16) * 32 + quad * 8];
        #pragma unroll
        for (int nt = 0; nt < 4; ++nt)
            bfr[nt] = *(const short8*)&Bs[(wn + nt * 16 + l16) * 32 + quad * 8];
        #pragma unroll
        for (int mt = 0; mt < 4; ++mt)
            #pragma unroll
            for (int nt = 0; nt < 4; ++nt)
                acc[mt][nt] = __builtin_amdgcn_mfma_f32_16x16x32_bf16(
                    af[mt], bfr[nt], acc[mt][nt], 0, 0, 0);
        __syncthreads();
    }

    // epilogue: D row = wm+mt*16+quad*4+j, col = wn+nt*16+l16 (m89 mapping)
    #pragma unroll
    for (int mt = 0; mt < 4; ++mt) {
        #pragma unroll
        for (int j = 0; j < 4; ++j) {
            const int row = bm0 + wm + mt * 16 + quad * 4 + j;
            if (row >= M) continue;
            #pragma unroll
            for (int nt = 0; nt < 4; ++nt) {
                const int col = bn0 + wn + nt * 16 + l16;
                const float val = acc[mt][nt][j] + bias[col];
                if (c_bf16) ((ushort_t*)C)[(size_t)row * Nc + col] = f2bf(val);
                else        ((float*)C)[(size_t)row * Nc + col]    = val;
            }
        }
    }
}

// Fused projection GEMMs: y<2 -> vproj = v@W_in (bf16 out, Nc=256);
// y in 2..4 -> offlog = q@[W_off|W_attn] (fp32 out, Nc=384).
__global__ __launch_bounds__(256) void gemm_proj_kernel(
    const ushort_t* __restrict__ vbf, const ushort_t* __restrict__ qbf,
    const ushort_t* __restrict__ Tin, const ushort_t* __restrict__ Tcomb,
    const float* __restrict__ b_in, const float* __restrict__ bcomb,
    ushort_t* __restrict__ vproj, float* __restrict__ offlog)
{
    __shared__ ushort_t As[128 * 32];
    __shared__ ushort_t Bs[128 * 32];
    const int bm0 = blockIdx.x * 128;
    const int y = blockIdx.y;
    if (y < 2)
        gemm_tile_core(vbf, Tin, b_in, vproj, true, M_TOT, 256, bm0, y * 128, 256, As, Bs);
    else
        gemm_tile_core(qbf, Tcomb, bcomb, offlog, false, M_TOT, 384, bm0, (y - 2) * 128, 256, As, Bs);
}

__global__ __launch_bounds__(256) void gemm_out_kernel(
    const ushort_t* __restrict__ mid, const ushort_t* __restrict__ Tout,
    const float* __restrict__ b_out, float* __restrict__ out)
{
    __shared__ ushort_t As[128 * 32];
    __shared__ ushort_t Bs[128 * 32];
    gemm_tile_core(mid, Tout, b_out, out, false, M_TOT, 256,
                   blockIdx.x * 128, blockIdx.y * 128, 256, As, Bs);
}

// =====================================================================
// Sampling kernel v5: 2 queries per 128-thread block (half the LDS,
// half the barrier width vs v4).  bf16 vproj gathers (8 B/lane).
// =====================================================================
#define QB 2
#define SLOTS 576

__global__ __launch_bounds__(128) void msda_sample_kernel(
    const ushort_t* __restrict__ vproj, const float* __restrict__ offlog,
    const float* __restrict__ p, ushort_t* __restrict__ mid)
{
    __shared__ float s_logit[QB][128];
    __shared__ float s_off[QB][256];
    __shared__ float s_p[QB][8];
    __shared__ float s_mx[QB][HEADS];
    __shared__ float s_inv[QB][HEADS];
    __shared__ float s_w[QB][SLOTS];
    __shared__ int   s_idx[QB][SLOTS];

    const int tid = threadIdx.x;          // 0..127
    const int bq0 = blockIdx.x * QB;

    #pragma unroll
    for (int i = tid; i < QB * 256; i += 128) {
        int sub = i >> 8, j = i & 255;
        s_off[sub][j] = offlog[(size_t)(bq0 + sub) * 384 + j];
    }
    #pragma unroll
    for (int i = tid; i < QB * 128; i += 128) {
        int sub = i >> 7, j = i & 127;
        s_logit[sub][j] = offlog[(size_t)(bq0 + sub) * 384 + 256 + j];
    }
    if (tid < QB * 8) {
        int sub = tid >> 3, j = tid & 7;
        s_p[sub][j] = p[(size_t)(bq0 + sub) * 8 + j];
    }
    __syncthreads();

    if (tid < QB * HEADS) {
        int sub = tid >> 3, h = tid & 7;
        float mx = -1e30f;
        #pragma unroll
        for (int i = 0; i < 16; ++i) mx = fmaxf(mx, s_logit[sub][h * 16 + i]);
        float ssum = 0.0f;
        #pragma unroll
        for (int i = 0; i < 16; ++i) ssum += __expf(s_logit[sub][h * 16 + i] - mx);
        s_mx[sub][h] = mx;
        s_inv[sub][h] = 1.0f / ssum;
    }
    __syncthreads();

    // ---- phase 1: 256 tasks (sub, h, l, pt) over 128 threads ----
    #pragma unroll
    for (int tt = tid; tt < QB * 128; tt += 128) {
        const int sub = tt >> 7;
        const int j   = tt & 127;          // h*16 + l*4 + pt
        const int h   = j >> 4;
        const int l   = (j >> 2) & 3;
        const int nq  = bq0 + sub;
        const int nb  = (nq >= QN) ? 1 : 0;

        const int Hl = c_Hl[l], Wl = c_Wl[l], st = c_start[l];
        const float fW = (float)Wl, fH = (float)Hl;

        const float w = __expf(s_logit[sub][j] - s_mx[sub][h]) * s_inv[sub][h];

        const int oi = j * 2;
        const float ox = s_off[sub][oi];
        const float oy = s_off[sub][oi + 1];
        const float px = s_p[sub][l * 2 + 0];
        const float py = s_p[sub][l * 2 + 1];

        const float lx = px + ox / fW;
        const float ly = py + oy / fH;
        const float x = lx * fW - 0.5f;
        const float y = ly * fH - 0.5f;

        const float x0f = floorf(x), y0f = floorf(y);
        const int x0 = (int)x0f, y0 = (int)y0f;
        const float dx = x - x0f, dy = y - y0f;

        const int base = nb * (HW_TOT * DIMS) + h * CH;
        const int slot = (j & 15) * 36 + h * 4;

        const bool vx0 = (x0 >= 0) & (x0 < Wl);
        const bool vx1 = (x0 + 1 >= 0) & (x0 + 1 < Wl);
        const bool vy0 = (y0 >= 0) & (y0 < Hl);
        const bool vy1 = (y0 + 1 >= 0) & (y0 + 1 < Hl);

        s_w[sub][slot + 0] = (vx0 & vy0) ? w * (1.0f - dx) * (1.0f - dy) : 0.0f;
        s_w[sub][slot + 1] = (vx1 & vy0) ? w * dx * (1.0f - dy) : 0.0f;
        s_w[sub][slot + 2] = (vx0 & vy1) ? w * (1.0f - dx) * dy : 0.0f;
        s_w[sub][slot + 3] = (vx1 & vy1) ? w * dx * dy : 0.0f;
        s_idx[sub][slot + 0] = (vx0 & vy0) ? base + (st + y0 * Wl + x0) * DIMS : 0;
        s_idx[sub][slot + 1] = (vx1 & vy0) ? base + (st + y0 * Wl + x0 + 1) * DIMS : 0;
        s_idx[sub][slot + 2] = (vx0 & vy1) ? base + (st + (y0 + 1) * Wl + x0) * DIMS : 0;
        s_idx[sub][slot + 3] = (vx1 & vy1) ? base + (st + (y0 + 1) * Wl + x0 + 1) * DIMS : 0;
    }
    __syncthreads();

    // ---- phase 2: bf16 gathers (uint2 = 4 channels), fp32 accumulate ----
    const int sub  = tid >> 6;
    const int lane = tid & 63;
    const int h    = lane >> 3;
    const int c4   = lane & 7;
    const int nq   = bq0 + sub;

    float ax = 0.0f, ay = 0.0f, az = 0.0f, aw = 0.0f;
    const ushort_t* __restrict__ vb = vproj + c4 * 4;

    #pragma unroll
    for (int t = 0; t < 16; ++t) {
        const int slot = t * 36 + h * 4;
        const int4   I = *(const int4*)&s_idx[sub][slot];
        const float4 W = *(const float4*)&s_w[sub][slot];

        const uint2 g0 = *(const uint2*)(vb + I.x);
        const uint2 g1 = *(const uint2*)(vb + I.y);
        const uint2 g2 = *(const uint2*)(vb + I.z);
        const uint2 g3 = *(const uint2*)(vb + I.w);

        ax = fmaf(W.x, __uint_as_float(g0.x << 16), ax);
        ay = fmaf(W.x, __uint_as_float(g0.x & 0xffff0000u), ay);
        az = fmaf(W.x, __uint_as_float(g0.y << 16), az);
        aw = fmaf(W.x, __uint_as_float(g0.y & 0xffff0000u), aw);

        ax = fmaf(W.y, __uint_as_float(g1.x << 16), ax);
        ay = fmaf(W.y, __uint_as_float(g1.x & 0xffff0000u), ay);
        az = fmaf(W.y, __uint_as_float(g1.y << 16), az);
        aw = fmaf(W.y, __uint_as_float(g1.y & 0xffff0000u), aw);

        ax = fmaf(W.z, __uint_as_float(g2.x << 16), ax);
        ay = fmaf(W.z, __uint_as_float(g2.x & 0xffff0000u), ay);
        az = fmaf(W.z, __uint_as_float(g2.y << 16), az);
        aw = fmaf(W.z, __uint_as_float(g2.y & 0xffff0000u), aw);

        ax = fmaf(W.w, __uint_as_float(g3.x << 16), ax);
        ay = fmaf(W.w, __uint_as_float(g3.x & 0xffff0000u), ay);
        az = fmaf(W.w, __uint_as_float(g3.y << 16), az);
        aw = fmaf(W.w, __uint_as_float(g3.y & 0xffff0000u), aw);
    }

    ushort_t mv[4] = {f2bf(ax), f2bf(ay), f2bf(az), f2bf(aw)};
    *(uint2*)&mid[(size_t)nq * DIMS + lane * 4] = *(uint2*)mv;
}

// =====================================================================
extern "C" void kernel_launch(void* const* d_in, const int* in_sizes, int n_in,
                              void* d_out, int out_size, void* d_ws, size_t ws_size,
                              hipStream_t stream)
{
    const float* q      = (const float*)d_in[0];
    const float* p      = (const float*)d_in[1];
    const float* v      = (const float*)d_in[2];
    const float* W_off  = (const float*)d_in[3];
    const float* b_off  = (const float*)d_in[4];
    const float* W_attn = (const float*)d_in[5];
    const float* b_attn = (const float*)d_in[6];
    const float* W_in   = (const float*)d_in[7];
    const float* b_in   = (const float*)d_in[8];
    const float* W_out  = (const float*)d_in[9];
    const float* b_out  = (const float*)d_in[10];
    float* out = (float*)d_out;

    const int M = M_TOT;                            // 24480

    // workspace layout (mid aliases vbf -- vbf dead after proj GEMM)
    ushort_t* vproj  = (ushort_t*)d_ws;                          // M*256 bf16
    float*    offlog = (float*)(vproj + (size_t)M * 256);        // M*384 f32
    ushort_t* vbf    = (ushort_t*)(offlog + (size_t)M * 384);    // M*256 bf16
    ushort_t* mid    = vbf;                                      // alias
    ushort_t* qbf    = vbf + (size_t)M * 256;                    // M*256 bf16
    ushort_t* Tin    = qbf + (size_t)M * 256;
    ushort_t* Tcomb  = Tin + 256 * 256;
    ushort_t* Tout   = Tcomb + 384 * 256;
    float*    bcomb  = (float*)(Tout + 256 * 256);

    // 0a) v,q -> bf16
    convert_qv_kernel<<<dim3(6120), 256, 0, stream>>>(v, q, vbf, qbf);
    // 0b) weights -> transposed bf16 (+ fused off/attn weight & bias)
    prep_weights_kernel<<<dim3(384, 1, 3), 256, 0, stream>>>(
        W_in, W_off, W_attn, W_out, b_off, b_attn, Tin, Tcomb, Tout, bcomb);

    // 1+2+3) fused projection GEMMs (m97-style)
    gemm_proj_kernel<<<dim3(192, 5), 256, 0, stream>>>(
        vbf, qbf, Tin, Tcomb, b_in, bcomb, vproj, offlog);
    // 4) softmax + bilinear sampling -> bf16 mid
    msda_sample_kernel<<<dim3(M / QB), 128, 0, stream>>>(vproj, offlog, p, mid);
    // 5) out = mid @ W_out + b_out
    gemm_out_kernel<<<dim3(192, 2), 256, 0, stream>>>(mid, Tout, b_out, out);
}